// Round 7
// baseline (330.645 us; speedup 1.0000x reference)
//
#include <hip/hip_runtime.h>
#include <math.h>

#define B_ 2
#define L_ 2048
#define E_ 2048
#define HQ 16
#define HKV 2
#define DH 128

typedef unsigned short u16;
typedef unsigned int u32;
typedef __attribute__((ext_vector_type(8))) short short8;
typedef __attribute__((ext_vector_type(4))) float f32x4;
typedef __attribute__((ext_vector_type(16))) float f32x16;
typedef __attribute__((ext_vector_type(4))) u32 u32x4;

static __device__ __forceinline__ u16 f2bf(float f) {
  unsigned int u = __float_as_uint(f);
  unsigned int r = (u + 0x7fffu + ((u >> 16) & 1u)) >> 16;
  return (u16)r;
}
static __device__ __forceinline__ float bf2f(u16 v) {
  return __uint_as_float(((u32)v) << 16);
}

static __device__ __forceinline__ u32 cvt_pk_bf16(float lo, float hi) {
  u32 r;
  asm volatile("v_cvt_pk_bf16_f32 %0, %1, %2" : "=v"(r) : "v"(lo), "v"(hi));
  return r;
}
// swaps a's upper-half lanes with b's lower-half lanes (gfx950).
// ONLY used with distinct-valued operands (validated in R5 T12 path).
static __device__ __forceinline__ void permswap(u32& a, u32& b) {
  asm volatile("v_permlane32_swap_b32 %0, %1" : "+v"(a), "+v"(b));
}

#define GLB(p) ((const __attribute__((address_space(1))) void*)(p))
#define LDS(p) ((__attribute__((address_space(3))) void*)(p))

// ---------------------------------------------------------------------------
// fp32 -> bf16 convert
// ---------------------------------------------------------------------------
__global__ void cvt_bf16_kernel(const float* __restrict__ in,
                                u16* __restrict__ out, int n) {
  int i = (blockIdx.x * 256 + threadIdx.x) * 8;
  if (i >= n) return;
  float4 a = *reinterpret_cast<const float4*>(in + i);
  float4 b = *reinterpret_cast<const float4*>(in + i + 4);
  short8 r;
  r[0] = (short)f2bf(a.x); r[1] = (short)f2bf(a.y);
  r[2] = (short)f2bf(a.z); r[3] = (short)f2bf(a.w);
  r[4] = (short)f2bf(b.x); r[5] = (short)f2bf(b.y);
  r[6] = (short)f2bf(b.z); r[7] = (short)f2bf(b.w);
  *reinterpret_cast<short8*>(out + i) = r;
}

// ---------------------------------------------------------------------------
// RoPE table
// ---------------------------------------------------------------------------
__global__ void rope_tab_kernel(float* __restrict__ ctab, float* __restrict__ stab) {
  int idx = blockIdx.x * 256 + threadIdx.x;
  if (idx >= L_ * (DH / 2)) return;
  int pos = idx >> 6;
  int f = idx & 63;
  float inv_freq = powf(10000.0f, -(float)f * (1.0f / 64.0f));
  float ang = (float)pos * inv_freq;
  float s, c;
  sincosf(ang, &s, &c);
  ctab[idx] = c;
  stab[idx] = s;
}

// ---------------------------------------------------------------------------
// RoPE apply from bf16 fused-qkv buffer -> bf16 head-major buffer
// ---------------------------------------------------------------------------
__global__ void rope_convert_kernel(const u16* __restrict__ in,
                                    u16* __restrict__ outb,
                                    const float* __restrict__ ctab,
                                    const float* __restrict__ stab,
                                    int H, int rowStride, int colOff,
                                    float scale, int total) {
  int idx = blockIdx.x * 256 + threadIdx.x;
  if (idx >= total) return;
  int f = idx & 63;
  int row = idx >> 6;
  int h = row % H;
  int bl = row / H;
  int l = bl & (L_ - 1);
  size_t sbase = (size_t)bl * rowStride + colOff + (size_t)h * DH;
  size_t dbase = (size_t)bl * ((size_t)H * DH) + (size_t)h * DH;
  float x1 = bf2f(in[sbase + f]);
  float x2 = bf2f(in[sbase + 64 + f]);
  float c = ctab[l * 64 + f];
  float s = stab[l * 64 + f];
  outb[dbase + f]      = f2bf((x1 * c - x2 * s) * scale);
  outb[dbase + 64 + f] = f2bf((x2 * c + x1 * s) * scale);
}

// ---------------------------------------------------------------------------
// V transpose from bf16 qkv buffer: -> Vt[(b*HKV+kvh)*128+d][key]
// ---------------------------------------------------------------------------
__global__ __launch_bounds__(256) void transpose_v_kernel(
    const u16* __restrict__ v, u16* __restrict__ Vt,
    int rowStride, int colOff) {
  __shared__ u16 tile[64][68];
  const int k0 = blockIdx.x * 64;
  const int d0 = blockIdx.y * 64;
  const int bk = blockIdx.z;
  const int b = bk / HKV, kvh = bk % HKV;
#pragma unroll
  for (int i = 0; i < 4; ++i) {
    int key = i * 16 + (threadIdx.x >> 4);
    int d4 = (threadIdx.x & 15) * 4;
    *reinterpret_cast<ushort2*>(&tile[key][d4]) = *reinterpret_cast<const ushort2*>(
        &v[(size_t)(b * L_ + k0 + key) * rowStride + colOff + kvh * DH + d0 + d4]);
    *reinterpret_cast<ushort2*>(&tile[key][d4 + 2]) = *reinterpret_cast<const ushort2*>(
        &v[(size_t)(b * L_ + k0 + key) * rowStride + colOff + kvh * DH + d0 + d4 + 2]);
  }
  __syncthreads();
  const int d = threadIdx.x >> 2;
  const int kq = (threadIdx.x & 3) * 16;
  u16* orow = Vt + ((size_t)(bk * DH + d0 + d)) * L_ + k0 + kq;
#pragma unroll
  for (int j = 0; j < 16; ++j) orow[j] = tile[kq + j][d];
}

// ---------------------------------------------------------------------------
// bf16 MFMA GEMM (m97 structure), templated output dtype
// ---------------------------------------------------------------------------
#define GBM 128
#define GBN 128
#define GBK 32

template <bool BF16OUT>
__global__ __launch_bounds__(256) void gemm_bf16_kernel(
    const u16* __restrict__ A, const u16* __restrict__ W,
    const float* __restrict__ bias, void* __restrict__ Cv,
    int M, int N, int K)
{
  __shared__ u16 As[GBM][GBK];
  __shared__ u16 Bs[GBN][GBK];
  const int tid = threadIdx.x;
  const int wave = tid >> 6;
  const int lane = tid & 63;
  const int lr = lane & 15;
  const int lg = lane >> 4;
  const int bm = blockIdx.y * GBM;
  const int bn = blockIdx.x * GBN;
  const int wm = (wave >> 1) * 64;
  const int wn = (wave & 1) * 64;

  const int srow = wave * 16 + (lane >> 2);
  const int scol = (lane & 3) * 8;
  const u16* ga = A + (size_t)(bm + srow) * K + scol;
  const u16* gb = W + (size_t)(bn + srow) * K + scol;
  u16* lA0 = &As[wave * 16][0];
  u16* lA1 = &As[64 + wave * 16][0];
  u16* lB0 = &Bs[wave * 16][0];
  u16* lB1 = &Bs[64 + wave * 16][0];

  f32x4 acc[4][4];
#pragma unroll
  for (int i = 0; i < 4; ++i)
#pragma unroll
    for (int j = 0; j < 4; ++j) acc[i][j] = (f32x4){0.f, 0.f, 0.f, 0.f};

  for (int k0 = 0; k0 < K; k0 += GBK) {
    __syncthreads();
    __builtin_amdgcn_global_load_lds(GLB(ga + k0), LDS(lA0), 16, 0, 0);
    __builtin_amdgcn_global_load_lds(GLB(ga + k0 + (size_t)64 * K), LDS(lA1), 16, 0, 0);
    __builtin_amdgcn_global_load_lds(GLB(gb + k0), LDS(lB0), 16, 0, 0);
    __builtin_amdgcn_global_load_lds(GLB(gb + k0 + (size_t)64 * K), LDS(lB1), 16, 0, 0);
    __syncthreads();

    short8 af[4], bf[4];
#pragma unroll
    for (int mi = 0; mi < 4; ++mi)
      af[mi] = *reinterpret_cast<const short8*>(&As[wm + mi * 16 + lr][lg * 8]);
#pragma unroll
    for (int ni = 0; ni < 4; ++ni)
      bf[ni] = *reinterpret_cast<const short8*>(&Bs[wn + ni * 16 + lr][lg * 8]);
#pragma unroll
    for (int mi = 0; mi < 4; ++mi)
#pragma unroll
      for (int ni = 0; ni < 4; ++ni)
        acc[mi][ni] = __builtin_amdgcn_mfma_f32_16x16x32_bf16(af[mi], bf[ni], acc[mi][ni], 0, 0, 0);
  }

#pragma unroll
  for (int ni = 0; ni < 4; ++ni) {
    int col = bn + wn + ni * 16 + lr;
    float bv = (bias != nullptr) ? bias[col] : 0.f;
#pragma unroll
    for (int mi = 0; mi < 4; ++mi) {
#pragma unroll
      for (int r = 0; r < 4; ++r) {
        int row = bm + wm + mi * 16 + lg * 4 + r;
        float val = acc[mi][ni][r] + bv;
        if constexpr (BF16OUT)
          ((u16*)Cv)[(size_t)row * N + col] = f2bf(val);
        else
          ((float*)Cv)[(size_t)row * N + col] = val;
      }
    }
  }
}

// ---------------------------------------------------------------------------
// Flash attention, 32x32x16 MFMA, swapped QK^T => lane-local softmax.
// One wave (64 thr) per 32-row Q tile; 2048 blocks, work-balanced ordering
// (block g<1024 -> heavy tile 63-pb, g>=1024 -> light tile pb).
// Cross-half reductions via __shfl_xor(,32) (R5-validated); sum merge
// deferred to epilogue; permlane32_swap only in T12 P-redistribution.
// ---------------------------------------------------------------------------
__device__ __forceinline__ void load_kt32(short8 dst[8], const u16* kbase, int j0) {
  const u16* kp = kbase + (size_t)j0 * (HKV * DH);
#pragma unroll
  for (int s = 0; s < 8; ++s)
    dst[s] = *reinterpret_cast<const short8*>(kp + s * 16);
}

__device__ __forceinline__ void attn_step32(
    const short8 qB[8], const short8 kc[8], const u16* vbase,
    int j0, int q0, int l5, int hi, float* cbuf,
    f32x16 O[4], float& mrun, float& lrun)
{
  short8 vv[8];
  {
    const u16* vp = vbase + j0;
#pragma unroll
    for (int n = 0; n < 4; ++n) {
#pragma unroll
      for (int c = 0; c < 2; ++c)
        vv[n * 2 + c] = *reinterpret_cast<const short8*>(
            vp + (size_t)(n * 32) * L_ + c * 16);
    }
  }

  f32x16 accl, acch;
#pragma unroll
  for (int r = 0; r < 16; ++r) { accl[r] = 0.f; acch[r] = 0.f; }
#pragma unroll
  for (int s = 0; s < 4; ++s)
    accl = __builtin_amdgcn_mfma_f32_32x32x16_bf16(kc[s], qB[s], accl, 0, 0, 0);
#pragma unroll
  for (int s = 4; s < 8; ++s)
    acch = __builtin_amdgcn_mfma_f32_32x32x16_bf16(kc[s], qB[s], acch, 0, 0, 0);

  float S[16];
#pragma unroll
  for (int r = 0; r < 16; ++r) S[r] = accl[r] + acch[r];

  if (j0 == q0) {
#pragma unroll
    for (int r = 0; r < 16; ++r) {
      int crow = (r & 3) + 8 * (r >> 2) + 4 * hi;
      if (crow > l5) S[r] = -INFINITY;
    }
  }

  // row max: in-register tree + one cross-half exchange (shfl, validated)
  float t8[8], t4[4], t2[2];
#pragma unroll
  for (int r = 0; r < 8; ++r) t8[r] = fmaxf(S[2 * r], S[2 * r + 1]);
#pragma unroll
  for (int r = 0; r < 4; ++r) t4[r] = fmaxf(t8[2 * r], t8[2 * r + 1]);
  t2[0] = fmaxf(t4[0], t4[1]); t2[1] = fmaxf(t4[2], t4[3]);
  float pmax = fmaxf(t2[0], t2[1]);
  pmax = fmaxf(pmax, __shfl_xor(pmax, 32));

  // defer-max rescale (T13)
  if (__any(pmax > mrun + 8.0f)) {
    float mnew = fmaxf(mrun, pmax);
    float corr = __expf(mrun - mnew);
    mrun = mnew;
    lrun *= corr;
    if (hi == 0) cbuf[l5] = corr;
    float4 cr[4];
#pragma unroll
    for (int g = 0; g < 4; ++g)
      cr[g] = *reinterpret_cast<const float4*>(&cbuf[8 * g + 4 * hi]);
#pragma unroll
    for (int n = 0; n < 4; ++n)
#pragma unroll
      for (int r = 0; r < 16; ++r)
        O[n][r] *= (&cr[r >> 2].x)[r & 3];
  }

  // P = exp(S - m); per-half partial row sum (merge deferred to epilogue)
  float p[16];
#pragma unroll
  for (int r = 0; r < 16; ++r) p[r] = __expf(S[r] - mrun);
#pragma unroll
  for (int r = 0; r < 8; ++r) t8[r] = p[2 * r] + p[2 * r + 1];
#pragma unroll
  for (int r = 0; r < 4; ++r) t4[r] = t8[2 * r] + t8[2 * r + 1];
  t2[0] = t4[0] + t4[1]; t2[1] = t4[2] + t4[3];
  lrun += t2[0] + t2[1];

  // pack to bf16 + redistribute into PV A-fragments (T12, R5-validated)
  u32 w[8];
#pragma unroll
  for (int t = 0; t < 8; ++t) w[t] = cvt_pk_bf16(p[2 * t], p[2 * t + 1]);
  permswap(w[0], w[2]); permswap(w[1], w[3]);
  permswap(w[4], w[6]); permswap(w[5], w[7]);
  short8 pa0 = __builtin_bit_cast(short8, (u32x4){w[0], w[1], w[2], w[3]});
  short8 pa1 = __builtin_bit_cast(short8, (u32x4){w[4], w[5], w[6], w[7]});

#pragma unroll
  for (int n = 0; n < 4; ++n) {
    O[n] = __builtin_amdgcn_mfma_f32_32x32x16_bf16(pa0, vv[n * 2 + 0], O[n], 0, 0, 0);
    O[n] = __builtin_amdgcn_mfma_f32_32x32x16_bf16(pa1, vv[n * 2 + 1], O[n], 0, 0, 0);
  }
}

__global__ __launch_bounds__(64) void flash_attn_mfma32_kernel(
    const u16* __restrict__ Qb, const u16* __restrict__ Kb,
    const u16* __restrict__ Vt, u16* __restrict__ ab)
{
  const int lane = threadIdx.x & 63;
  const int l5 = lane & 31;
  const int hi = lane >> 5;
  // balanced mapping: g<1024 -> heavy tile (63-pb), g>=1024 -> light tile pb
  const int g = blockIdx.x;
  const int half = g >> 10;
  const int u = g & 1023;
  const int pb = u & 31;
  const int h = (u >> 5) & 15;
  const int b = u >> 9;
  const int tile = half ? pb : (63 - pb);
  const int q0 = 32 * tile;
  const int kvh = h >> 3;

  __shared__ __align__(16) float cbuf[32];

  const u16* kbase = Kb + ((size_t)(b * L_ + l5)) * (HKV * DH) + kvh * DH + hi * 8;
  const u16* vbase = Vt + ((size_t)((b * HKV + kvh) * DH + l5)) * L_ + hi * 8;

  const u16* qrow = Qb + ((size_t)(b * L_ + q0 + l5)) * (HQ * DH) + h * DH + hi * 8;
  short8 qB[8];
#pragma unroll
  for (int s = 0; s < 8; ++s)
    qB[s] = *reinterpret_cast<const short8*>(qrow + s * 16);

  f32x16 O[4];
#pragma unroll
  for (int n = 0; n < 4; ++n)
#pragma unroll
    for (int r = 0; r < 16; ++r) O[n][r] = 0.f;
  float mrun = -INFINITY, lrun = 0.f;

  const int nst = tile + 1;
  short8 ka[8], kb2[8];
  load_kt32(ka, kbase, 0);
  int i = 0;
  while (true) {
    if (i + 1 < nst) load_kt32(kb2, kbase, (i + 1) * 32);
    attn_step32(qB, ka, vbase, i * 32, q0, l5, hi, cbuf, O, mrun, lrun);
    ++i; if (i >= nst) break;
    if (i + 1 < nst) load_kt32(ka, kbase, (i + 1) * 32);
    attn_step32(qB, kb2, vbase, i * 32, q0, l5, hi, cbuf, O, mrun, lrun);
    ++i; if (i >= nst) break;
  }

  // epilogue: merge per-half partial sums, broadcast via LDS, divide, store
  float ltot = lrun + __shfl_xor(lrun, 32);
  if (hi == 0) cbuf[l5] = ltot;
  float4 lv[4];
#pragma unroll
  for (int gg = 0; gg < 4; ++gg)
    lv[gg] = *reinterpret_cast<const float4*>(&cbuf[8 * gg + 4 * hi]);

  u16* obase = ab + (size_t)(b * L_ + q0) * (HQ * DH) + h * DH;
#pragma unroll
  for (int r = 0; r < 16; ++r) {
    int crow = (r & 3) + 8 * (r >> 2) + 4 * hi;
    float inv = __builtin_amdgcn_rcpf((&lv[r >> 2].x)[r & 3]);
    u16* orow = obase + (size_t)crow * (HQ * DH) + l5;
#pragma unroll
    for (int n = 0; n < 4; ++n)
      orow[n * 32] = f2bf(O[n][r] * inv);
  }
}

// ---------------------------------------------------------------------------
// launch
// ---------------------------------------------------------------------------
extern "C" void kernel_launch(void* const* d_in, const int* in_sizes, int n_in,
                              void* d_out, int out_size, void* d_ws, size_t ws_size,
                              hipStream_t stream) {
  const float* x  = (const float*)d_in[0];
  const float* wq = (const float*)d_in[1];
  const float* wk = (const float*)d_in[2];
  const float* wv = (const float*)d_in[3];
  const float* wo = (const float*)d_in[4];
  const float* bq = (const float*)d_in[5];
  const float* bk = (const float*)d_in[6];
  const float* bv = (const float*)d_in[7];
  float* out = (float*)d_out;

  const int M = B_ * L_;
  const int NQKV = HQ * DH + 2 * HKV * DH;  // 2560
  const size_t QN = (size_t)B_ * L_ * HQ * DH;
  const size_t KN = (size_t)B_ * L_ * HKV * DH;
  const size_t TN = (size_t)L_ * (DH / 2);

  float* ws = (float*)d_ws;
  float* ct   = ws;
  float* st   = ct + TN;
  float* bqkv = st + TN;
  u16* qkvb   = (u16*)(bqkv + 2560);        // bf16 QKV projection output
  u16* xb     = qkvb + (size_t)M * NQKV;
  u16* wqkvb  = xb + (size_t)M * E_;
  u16* Qbf    = wqkvb + (size_t)NQKV * E_;
  u16* Kbf    = Qbf + QN;
  u16* Vt     = Kbf + KN;
  u16* ab     = qkvb;   // alias: qkvb dead after rope/transpose
  u16* wob    = Qbf;    // alias: Qbf dead after attention

  const float scale = 0.08838834764831845f;

  rope_tab_kernel<<<(L_ * (DH / 2) + 255) / 256, 256, 0, stream>>>(ct, st);

  cvt_bf16_kernel<<<(int)(QN / 8 / 256), 256, 0, stream>>>(x, xb, (int)QN);
  cvt_bf16_kernel<<<(HQ * DH * E_) / 8 / 256, 256, 0, stream>>>(wq, wqkvb, HQ * DH * E_);
  cvt_bf16_kernel<<<(HKV * DH * E_) / 8 / 256, 256, 0, stream>>>(
      wk, wqkvb + (size_t)(HQ * DH) * E_, HKV * DH * E_);
  cvt_bf16_kernel<<<(HKV * DH * E_) / 8 / 256, 256, 0, stream>>>(
      wv, wqkvb + (size_t)(HQ * DH + HKV * DH) * E_, HKV * DH * E_);

  hipMemcpyAsync(bqkv, bq, (size_t)HQ * DH * 4, hipMemcpyDeviceToDevice, stream);
  hipMemcpyAsync(bqkv + HQ * DH, bk, (size_t)HKV * DH * 4, hipMemcpyDeviceToDevice, stream);
  hipMemcpyAsync(bqkv + HQ * DH + HKV * DH, bv, (size_t)HKV * DH * 4, hipMemcpyDeviceToDevice, stream);

  gemm_bf16_kernel<true><<<dim3(NQKV / GBN, M / GBM), 256, 0, stream>>>(
      xb, wqkvb, bqkv, qkvb, M, NQKV, E_);

  {
    int totq = B_ * L_ * HQ * 64;
    rope_convert_kernel<<<(totq + 255) / 256, 256, 0, stream>>>(
        qkvb, Qbf, ct, st, HQ, NQKV, 0, scale, totq);
    int totk = B_ * L_ * HKV * 64;
    rope_convert_kernel<<<(totk + 255) / 256, 256, 0, stream>>>(
        qkvb, Kbf, ct, st, HKV, NQKV, HQ * DH, 1.0f, totk);
  }
  transpose_v_kernel<<<dim3(L_ / 64, DH / 64, B_ * HKV), 256, 0, stream>>>(
      qkvb, Vt, NQKV, HQ * DH + HKV * DH);

  flash_attn_mfma32_kernel<<<dim3(2048), 64, 0, stream>>>(Qbf, Kbf, Vt, ab);

  cvt_bf16_kernel<<<(E_ * E_) / 8 / 256, 256, 0, stream>>>(wo, wob, E_ * E_);
  gemm_bf16_kernel<false><<<dim3(E_ / GBN, M / GBM), 256, 0, stream>>>(
      ab, wob, nullptr, out, M, E_, E_);
}

// Round 8
// 306.153 us; speedup vs baseline: 1.0800x; 1.0800x over previous
//
#include <hip/hip_runtime.h>
#include <math.h>

#define B_ 2
#define L_ 2048
#define E_ 2048
#define HQ 16
#define HKV 2
#define DH 128

typedef unsigned short u16;
typedef unsigned int u32;
typedef __attribute__((ext_vector_type(8))) short short8;
typedef __attribute__((ext_vector_type(4))) float f32x4;
typedef __attribute__((ext_vector_type(16))) float f32x16;
typedef __attribute__((ext_vector_type(4))) u32 u32x4;

static __device__ __forceinline__ u16 f2bf(float f) {
  unsigned int u = __float_as_uint(f);
  unsigned int r = (u + 0x7fffu + ((u >> 16) & 1u)) >> 16;
  return (u16)r;
}
static __device__ __forceinline__ float bf2f(u16 v) {
  return __uint_as_float(((u32)v) << 16);
}

static __device__ __forceinline__ u32 cvt_pk_bf16(float lo, float hi) {
  u32 r;
  asm volatile("v_cvt_pk_bf16_f32 %0, %1, %2" : "=v"(r) : "v"(lo), "v"(hi));
  return r;
}
// swaps a's upper-half lanes with b's lower-half lanes (gfx950).
// ONLY used with distinct-valued operands (validated R5 T12 path).
static __device__ __forceinline__ void permswap(u32& a, u32& b) {
  asm volatile("v_permlane32_swap_b32 %0, %1" : "+v"(a), "+v"(b));
}

#define GLB(p) ((const __attribute__((address_space(1))) void*)(p))
#define LDS(p) ((__attribute__((address_space(3))) void*)(p))

// ---------------------------------------------------------------------------
// fp32 -> bf16 convert
// ---------------------------------------------------------------------------
__global__ void cvt_bf16_kernel(const float* __restrict__ in,
                                u16* __restrict__ out, int n) {
  int i = (blockIdx.x * 256 + threadIdx.x) * 8;
  if (i >= n) return;
  float4 a = *reinterpret_cast<const float4*>(in + i);
  float4 b = *reinterpret_cast<const float4*>(in + i + 4);
  short8 r;
  r[0] = (short)f2bf(a.x); r[1] = (short)f2bf(a.y);
  r[2] = (short)f2bf(a.z); r[3] = (short)f2bf(a.w);
  r[4] = (short)f2bf(b.x); r[5] = (short)f2bf(b.y);
  r[6] = (short)f2bf(b.z); r[7] = (short)f2bf(b.w);
  *reinterpret_cast<short8*>(out + i) = r;
}

// ---------------------------------------------------------------------------
// RoPE table
// ---------------------------------------------------------------------------
__global__ void rope_tab_kernel(float* __restrict__ ctab, float* __restrict__ stab) {
  int idx = blockIdx.x * 256 + threadIdx.x;
  if (idx >= L_ * (DH / 2)) return;
  int pos = idx >> 6;
  int f = idx & 63;
  float inv_freq = powf(10000.0f, -(float)f * (1.0f / 64.0f));
  float ang = (float)pos * inv_freq;
  float s, c;
  sincosf(ang, &s, &c);
  ctab[idx] = c;
  stab[idx] = s;
}

// ---------------------------------------------------------------------------
// RoPE apply from bf16 fused-qkv buffer -> bf16 head-major buffer
// ---------------------------------------------------------------------------
__global__ void rope_convert_kernel(const u16* __restrict__ in,
                                    u16* __restrict__ outb,
                                    const float* __restrict__ ctab,
                                    const float* __restrict__ stab,
                                    int H, int rowStride, int colOff,
                                    float scale, int total) {
  int idx = blockIdx.x * 256 + threadIdx.x;
  if (idx >= total) return;
  int f = idx & 63;
  int row = idx >> 6;
  int h = row % H;
  int bl = row / H;
  int l = bl & (L_ - 1);
  size_t sbase = (size_t)bl * rowStride + colOff + (size_t)h * DH;
  size_t dbase = (size_t)bl * ((size_t)H * DH) + (size_t)h * DH;
  float x1 = bf2f(in[sbase + f]);
  float x2 = bf2f(in[sbase + 64 + f]);
  float c = ctab[l * 64 + f];
  float s = stab[l * 64 + f];
  outb[dbase + f]      = f2bf((x1 * c - x2 * s) * scale);
  outb[dbase + 64 + f] = f2bf((x2 * c + x1 * s) * scale);
}

// ---------------------------------------------------------------------------
// V transpose from bf16 qkv buffer: -> Vt[(b*HKV+kvh)*128+d][key]
// ---------------------------------------------------------------------------
__global__ __launch_bounds__(256) void transpose_v_kernel(
    const u16* __restrict__ v, u16* __restrict__ Vt,
    int rowStride, int colOff) {
  __shared__ u16 tile[64][68];
  const int k0 = blockIdx.x * 64;
  const int d0 = blockIdx.y * 64;
  const int bk = blockIdx.z;
  const int b = bk / HKV, kvh = bk % HKV;
#pragma unroll
  for (int i = 0; i < 4; ++i) {
    int key = i * 16 + (threadIdx.x >> 4);
    int d4 = (threadIdx.x & 15) * 4;
    *reinterpret_cast<ushort2*>(&tile[key][d4]) = *reinterpret_cast<const ushort2*>(
        &v[(size_t)(b * L_ + k0 + key) * rowStride + colOff + kvh * DH + d0 + d4]);
    *reinterpret_cast<ushort2*>(&tile[key][d4 + 2]) = *reinterpret_cast<const ushort2*>(
        &v[(size_t)(b * L_ + k0 + key) * rowStride + colOff + kvh * DH + d0 + d4 + 2]);
  }
  __syncthreads();
  const int d = threadIdx.x >> 2;
  const int kq = (threadIdx.x & 3) * 16;
  u16* orow = Vt + ((size_t)(bk * DH + d0 + d)) * L_ + k0 + kq;
#pragma unroll
  for (int j = 0; j < 16; ++j) orow[j] = tile[kq + j][d];
}

// ---------------------------------------------------------------------------
// bf16 MFMA GEMM (m97 structure), templated output dtype
// ---------------------------------------------------------------------------
#define GBM 128
#define GBN 128
#define GBK 32

template <bool BF16OUT>
__global__ __launch_bounds__(256) void gemm_bf16_kernel(
    const u16* __restrict__ A, const u16* __restrict__ W,
    const float* __restrict__ bias, void* __restrict__ Cv,
    int M, int N, int K)
{
  __shared__ u16 As[GBM][GBK];
  __shared__ u16 Bs[GBN][GBK];
  const int tid = threadIdx.x;
  const int wave = tid >> 6;
  const int lane = tid & 63;
  const int lr = lane & 15;
  const int lg = lane >> 4;
  const int bm = blockIdx.y * GBM;
  const int bn = blockIdx.x * GBN;
  const int wm = (wave >> 1) * 64;
  const int wn = (wave & 1) * 64;

  const int srow = wave * 16 + (lane >> 2);
  const int scol = (lane & 3) * 8;
  const u16* ga = A + (size_t)(bm + srow) * K + scol;
  const u16* gb = W + (size_t)(bn + srow) * K + scol;
  u16* lA0 = &As[wave * 16][0];
  u16* lA1 = &As[64 + wave * 16][0];
  u16* lB0 = &Bs[wave * 16][0];
  u16* lB1 = &Bs[64 + wave * 16][0];

  f32x4 acc[4][4];
#pragma unroll
  for (int i = 0; i < 4; ++i)
#pragma unroll
    for (int j = 0; j < 4; ++j) acc[i][j] = (f32x4){0.f, 0.f, 0.f, 0.f};

  for (int k0 = 0; k0 < K; k0 += GBK) {
    __syncthreads();
    __builtin_amdgcn_global_load_lds(GLB(ga + k0), LDS(lA0), 16, 0, 0);
    __builtin_amdgcn_global_load_lds(GLB(ga + k0 + (size_t)64 * K), LDS(lA1), 16, 0, 0);
    __builtin_amdgcn_global_load_lds(GLB(gb + k0), LDS(lB0), 16, 0, 0);
    __builtin_amdgcn_global_load_lds(GLB(gb + k0 + (size_t)64 * K), LDS(lB1), 16, 0, 0);
    __syncthreads();

    short8 af[4], bf[4];
#pragma unroll
    for (int mi = 0; mi < 4; ++mi)
      af[mi] = *reinterpret_cast<const short8*>(&As[wm + mi * 16 + lr][lg * 8]);
#pragma unroll
    for (int ni = 0; ni < 4; ++ni)
      bf[ni] = *reinterpret_cast<const short8*>(&Bs[wn + ni * 16 + lr][lg * 8]);
#pragma unroll
    for (int mi = 0; mi < 4; ++mi)
#pragma unroll
      for (int ni = 0; ni < 4; ++ni)
        acc[mi][ni] = __builtin_amdgcn_mfma_f32_16x16x32_bf16(af[mi], bf[ni], acc[mi][ni], 0, 0, 0);
  }

#pragma unroll
  for (int ni = 0; ni < 4; ++ni) {
    int col = bn + wn + ni * 16 + lr;
    float bv = (bias != nullptr) ? bias[col] : 0.f;
#pragma unroll
    for (int mi = 0; mi < 4; ++mi) {
#pragma unroll
      for (int r = 0; r < 4; ++r) {
        int row = bm + wm + mi * 16 + lg * 4 + r;
        float val = acc[mi][ni][r] + bv;
        if constexpr (BF16OUT)
          ((u16*)Cv)[(size_t)row * N + col] = f2bf(val);
        else
          ((float*)Cv)[(size_t)row * N + col] = val;
      }
    }
  }
}

// ---------------------------------------------------------------------------
// Flash attention with LDS-shared K/V across heads.
// Block = 128 thr (2 waves) = one 32-row q-tile x 4 heads (2 heads/wave).
// Per step: K-tile (32x128) + V-tile (128x32) staged to LDS (double-buffered,
// XOR-swizzled via pre-swizzled global source); both waves consume.
// Swapped QK^T (mfma(K,Q)) lane-local softmax; T12 pack; T13 defer-max.
// Grid 512 blocks, heavy-tile-first; XCD-clustered (b,kvh) mapping.
// ---------------------------------------------------------------------------
__device__ __forceinline__ void head_step(
    const short8 qB[8], const short8 kc[8], const short8 vv[8],
    int j0, int q0, int l5, int hi, float* cbufw,
    f32x16 O[4], float& mrun, float& lrun)
{
  f32x16 accl, acch;
#pragma unroll
  for (int r = 0; r < 16; ++r) { accl[r] = 0.f; acch[r] = 0.f; }
#pragma unroll
  for (int s = 0; s < 4; ++s)
    accl = __builtin_amdgcn_mfma_f32_32x32x16_bf16(kc[s], qB[s], accl, 0, 0, 0);
#pragma unroll
  for (int s = 4; s < 8; ++s)
    acch = __builtin_amdgcn_mfma_f32_32x32x16_bf16(kc[s], qB[s], acch, 0, 0, 0);

  float S[16];
#pragma unroll
  for (int r = 0; r < 16; ++r) S[r] = accl[r] + acch[r];

  if (j0 == q0) {
#pragma unroll
    for (int r = 0; r < 16; ++r) {
      int crow = (r & 3) + 8 * (r >> 2) + 4 * hi;
      if (crow > l5) S[r] = -INFINITY;
    }
  }

  float t8[8], t4[4], t2[2];
#pragma unroll
  for (int r = 0; r < 8; ++r) t8[r] = fmaxf(S[2 * r], S[2 * r + 1]);
#pragma unroll
  for (int r = 0; r < 4; ++r) t4[r] = fmaxf(t8[2 * r], t8[2 * r + 1]);
  t2[0] = fmaxf(t4[0], t4[1]); t2[1] = fmaxf(t4[2], t4[3]);
  float pmax = fmaxf(t2[0], t2[1]);
  pmax = fmaxf(pmax, __shfl_xor(pmax, 32));

  if (__any(pmax > mrun + 8.0f)) {
    float mnew = fmaxf(mrun, pmax);
    float corr = __expf(mrun - mnew);
    mrun = mnew;
    lrun *= corr;
    if (hi == 0) cbufw[l5] = corr;
    float4 cr[4];
#pragma unroll
    for (int g = 0; g < 4; ++g)
      cr[g] = *reinterpret_cast<const float4*>(&cbufw[8 * g + 4 * hi]);
#pragma unroll
    for (int n = 0; n < 4; ++n)
#pragma unroll
      for (int r = 0; r < 16; ++r)
        O[n][r] *= (&cr[r >> 2].x)[r & 3];
  }

  float p[16];
#pragma unroll
  for (int r = 0; r < 16; ++r) p[r] = __expf(S[r] - mrun);
#pragma unroll
  for (int r = 0; r < 8; ++r) t8[r] = p[2 * r] + p[2 * r + 1];
#pragma unroll
  for (int r = 0; r < 4; ++r) t4[r] = t8[2 * r] + t8[2 * r + 1];
  t2[0] = t4[0] + t4[1]; t2[1] = t4[2] + t4[3];
  lrun += t2[0] + t2[1];

  u32 w[8];
#pragma unroll
  for (int t = 0; t < 8; ++t) w[t] = cvt_pk_bf16(p[2 * t], p[2 * t + 1]);
  permswap(w[0], w[2]); permswap(w[1], w[3]);
  permswap(w[4], w[6]); permswap(w[5], w[7]);
  short8 pa0 = __builtin_bit_cast(short8, (u32x4){w[0], w[1], w[2], w[3]});
  short8 pa1 = __builtin_bit_cast(short8, (u32x4){w[4], w[5], w[6], w[7]});

#pragma unroll
  for (int n = 0; n < 4; ++n) {
    O[n] = __builtin_amdgcn_mfma_f32_32x32x16_bf16(pa0, vv[n * 2 + 0], O[n], 0, 0, 0);
    O[n] = __builtin_amdgcn_mfma_f32_32x32x16_bf16(pa1, vv[n * 2 + 1], O[n], 0, 0, 0);
  }
}

__device__ __forceinline__ void head_epilogue(
    const f32x16 O[4], float lrun, int l5, int hi, float* cbufw,
    u16* __restrict__ obase)
{
  float ltot = lrun + __shfl_xor(lrun, 32);
  if (hi == 0) cbufw[l5] = ltot;
  float4 lv[4];
#pragma unroll
  for (int gg = 0; gg < 4; ++gg)
    lv[gg] = *reinterpret_cast<const float4*>(&cbufw[8 * gg + 4 * hi]);
#pragma unroll
  for (int r = 0; r < 16; ++r) {
    int crow = (r & 3) + 8 * (r >> 2) + 4 * hi;
    float inv = __builtin_amdgcn_rcpf((&lv[r >> 2].x)[r & 3]);
    u16* orow = obase + (size_t)crow * (HQ * DH) + l5;
#pragma unroll
    for (int n = 0; n < 4; ++n)
      orow[n * 32] = f2bf(O[n][r] * inv);
  }
}

__global__ __launch_bounds__(128) void flash_attn_lds_kernel(
    const u16* __restrict__ Qb, const u16* __restrict__ Kb,
    const u16* __restrict__ Vt, u16* __restrict__ ab)
{
  const int tid = threadIdx.x;
  const int wave = tid >> 6;
  const int lane = tid & 63;
  const int l5 = lane & 31;
  const int hi = lane >> 5;

  // mapping: g = (u<<3)|x ; x: xcd slot -> combo (b,kvh) + head-half; u: tile
  const int g = blockIdx.x;
  const int x = g & 7;
  const int u = g >> 3;              // 0..63
  const int t = 63 - u;              // tile index, heavy first
  const int c = x >> 1;              // combo 0..3
  const int hh = x & 1;              // head half
  const int b = c >> 1, kvh = c & 1;
  const int h0 = kvh * 8 + hh * 4 + wave * 2;   // this wave: heads h0, h0+1
  const int q0 = 32 * t;
  const int nst = t + 1;
  const int bk = b * HKV + kvh;

  __shared__ u16 Ks[2][32 * 128];    // swizzled: slot ^= key&7 (16B slots)
  __shared__ u16 Vs[2][128 * 32];    // swizzled: slot ^= (d>>1)&3
  __shared__ __align__(16) float cbuf[2][32];

  // Q for two heads, fragment layout as R5 (B-operand of swapped QK^T)
  short8 qA[8], qC[8];
  {
    const u16* qr0 = Qb + ((size_t)(b * L_ + q0 + l5)) * (HQ * DH) + h0 * DH + hi * 8;
    const u16* qr1 = qr0 + DH;
#pragma unroll
    for (int s = 0; s < 8; ++s) {
      qA[s] = *reinterpret_cast<const short8*>(qr0 + s * 16);
      qC[s] = *reinterpret_cast<const short8*>(qr1 + s * 16);
    }
  }

  const u16* Kg = Kb + (size_t)(b * L_) * (HKV * DH) + kvh * DH;
  const u16* Vg = Vt + (size_t)(bk * DH) * L_;

  f32x16 OA[4], OC[4];
#pragma unroll
  for (int n = 0; n < 4; ++n)
#pragma unroll
    for (int r = 0; r < 16; ++r) { OA[n][r] = 0.f; OC[n][r] = 0.f; }
  float mA = -INFINITY, lA = 0.f, mC = -INFINITY, lC = 0.f;

  // ---- staging: 512 chunks of 16B each for K and V; 2 waves x 4 calls ----
  auto stage = [&](int buf, int j0) {
#pragma unroll
    for (int q = 0; q < 4; ++q) {
      int i = q * 128 + wave * 64 + lane;              // K chunk 0..511
      int key = i >> 4, slot = i & 15;
      const u16* src = Kg + (size_t)(j0 + key) * (HKV * DH) + (slot ^ (key & 7)) * 8;
      __builtin_amdgcn_global_load_lds(GLB(src), LDS(&Ks[buf][(q * 128 + wave * 64) * 8]), 16, 0, 0);
    }
#pragma unroll
    for (int q = 0; q < 4; ++q) {
      int i = q * 128 + wave * 64 + lane;              // V chunk 0..511
      int d = i >> 2, slot = i & 3;
      const u16* src = Vg + (size_t)d * L_ + j0 + (slot ^ ((d >> 1) & 3)) * 8;
      __builtin_amdgcn_global_load_lds(GLB(src), LDS(&Vs[buf][(q * 128 + wave * 64) * 8]), 16, 0, 0);
    }
  };

  stage(0, 0);
  __syncthreads();

  int cur = 0;
  for (int i = 0; i < nst; ++i) {
    if (i + 1 < nst) stage(cur ^ 1, (i + 1) * 32);

    // K fragments (shared by both heads): row=l5, k-slot=(2s+hi), un-swizzle
    short8 kc[8], vv[8];
#pragma unroll
    for (int s = 0; s < 8; ++s) {
      int slot = (2 * s + hi) ^ (l5 & 7);
      kc[s] = *reinterpret_cast<const short8*>(&Ks[cur][l5 * 128 + slot * 8]);
    }
    // V fragments: row d = n*32+l5, key-slot=(2c+hi), un-swizzle
#pragma unroll
    for (int n = 0; n < 4; ++n) {
#pragma unroll
      for (int cc = 0; cc < 2; ++cc) {
        int d = n * 32 + l5;
        int slot = (cc * 2 + hi) ^ ((d >> 1) & 3);
        vv[n * 2 + cc] = *reinterpret_cast<const short8*>(&Vs[cur][d * 32 + slot * 8]);
      }
    }

    int j0 = i * 32;
    head_step(qA, kc, vv, j0, q0, l5, hi, cbuf[wave], OA, mA, lA);
    head_step(qC, kc, vv, j0, q0, l5, hi, cbuf[wave], OC, mC, lC);

    __syncthreads();
    cur ^= 1;
  }

  u16* ob0 = ab + (size_t)(b * L_ + q0) * (HQ * DH) + h0 * DH;
  head_epilogue(OA, lA, l5, hi, cbuf[wave], ob0);
  head_epilogue(OC, lC, l5, hi, cbuf[wave], ob0 + DH);
}

// ---------------------------------------------------------------------------
// launch
// ---------------------------------------------------------------------------
extern "C" void kernel_launch(void* const* d_in, const int* in_sizes, int n_in,
                              void* d_out, int out_size, void* d_ws, size_t ws_size,
                              hipStream_t stream) {
  const float* x  = (const float*)d_in[0];
  const float* wq = (const float*)d_in[1];
  const float* wk = (const float*)d_in[2];
  const float* wv = (const float*)d_in[3];
  const float* wo = (const float*)d_in[4];
  const float* bq = (const float*)d_in[5];
  const float* bk = (const float*)d_in[6];
  const float* bv = (const float*)d_in[7];
  float* out = (float*)d_out;

  const int M = B_ * L_;
  const int NQKV = HQ * DH + 2 * HKV * DH;  // 2560
  const size_t QN = (size_t)B_ * L_ * HQ * DH;
  const size_t KN = (size_t)B_ * L_ * HKV * DH;
  const size_t TN = (size_t)L_ * (DH / 2);

  float* ws = (float*)d_ws;
  float* ct   = ws;
  float* st   = ct + TN;
  float* bqkv = st + TN;
  u16* qkvb   = (u16*)(bqkv + 2560);        // bf16 QKV projection output
  u16* xb     = qkvb + (size_t)M * NQKV;
  u16* wqkvb  = xb + (size_t)M * E_;
  u16* Qbf    = wqkvb + (size_t)NQKV * E_;
  u16* Kbf    = Qbf + QN;
  u16* Vt     = Kbf + KN;
  u16* ab     = qkvb;   // alias: qkvb dead after rope/transpose
  u16* wob    = Qbf;    // alias: Qbf dead after attention

  const float scale = 0.08838834764831845f;

  rope_tab_kernel<<<(L_ * (DH / 2) + 255) / 256, 256, 0, stream>>>(ct, st);

  cvt_bf16_kernel<<<(int)(QN / 8 / 256), 256, 0, stream>>>(x, xb, (int)QN);
  cvt_bf16_kernel<<<(HQ * DH * E_) / 8 / 256, 256, 0, stream>>>(wq, wqkvb, HQ * DH * E_);
  cvt_bf16_kernel<<<(HKV * DH * E_) / 8 / 256, 256, 0, stream>>>(
      wk, wqkvb + (size_t)(HQ * DH) * E_, HKV * DH * E_);
  cvt_bf16_kernel<<<(HKV * DH * E_) / 8 / 256, 256, 0, stream>>>(
      wv, wqkvb + (size_t)(HQ * DH + HKV * DH) * E_, HKV * DH * E_);

  hipMemcpyAsync(bqkv, bq, (size_t)HQ * DH * 4, hipMemcpyDeviceToDevice, stream);
  hipMemcpyAsync(bqkv + HQ * DH, bk, (size_t)HKV * DH * 4, hipMemcpyDeviceToDevice, stream);
  hipMemcpyAsync(bqkv + HQ * DH + HKV * DH, bv, (size_t)HKV * DH * 4, hipMemcpyDeviceToDevice, stream);

  gemm_bf16_kernel<true><<<dim3(NQKV / GBN, M / GBM), 256, 0, stream>>>(
      xb, wqkvb, bqkv, qkvb, M, NQKV, E_);

  {
    int totq = B_ * L_ * HQ * 64;
    rope_convert_kernel<<<(totq + 255) / 256, 256, 0, stream>>>(
        qkvb, Qbf, ct, st, HQ, NQKV, 0, scale, totq);
    int totk = B_ * L_ * HKV * 64;
    rope_convert_kernel<<<(totk + 255) / 256, 256, 0, stream>>>(
        qkvb, Kbf, ct, st, HKV, NQKV, HQ * DH, 1.0f, totk);
  }
  transpose_v_kernel<<<dim3(L_ / 64, DH / 64, B_ * HKV), 256, 0, stream>>>(
      qkvb, Vt, NQKV, HQ * DH + HKV * DH);

  flash_attn_lds_kernel<<<dim3(512), 128, 0, stream>>>(Qbf, Kbf, Vt, ab);

  cvt_bf16_kernel<<<(E_ * E_) / 8 / 256, 256, 0, stream>>>(wo, wob, E_ * E_);
  gemm_bf16_kernel<false><<<dim3(E_ / GBN, M / GBM), 256, 0, stream>>>(
      ab, wob, nullptr, out, M, E_, E_);
}

// Round 9
// 253.647 us; speedup vs baseline: 1.3036x; 1.2070x over previous
//
#include <hip/hip_runtime.h>
#include <math.h>

#define B_ 2
#define L_ 2048
#define E_ 2048
#define HQ 16
#define HKV 2
#define DH 128

typedef unsigned short u16;
typedef unsigned int u32;
typedef __attribute__((ext_vector_type(8))) short short8;
typedef __attribute__((ext_vector_type(4))) float f32x4;
typedef __attribute__((ext_vector_type(16))) float f32x16;
typedef __attribute__((ext_vector_type(4))) u32 u32x4;

static __device__ __forceinline__ u16 f2bf(float f) {
  unsigned int u = __float_as_uint(f);
  unsigned int r = (u + 0x7fffu + ((u >> 16) & 1u)) >> 16;
  return (u16)r;
}
static __device__ __forceinline__ float bf2f(u16 v) {
  return __uint_as_float(((u32)v) << 16);
}

static __device__ __forceinline__ u32 cvt_pk_bf16(float lo, float hi) {
  u32 r;
  asm volatile("v_cvt_pk_bf16_f32 %0, %1, %2" : "=v"(r) : "v"(lo), "v"(hi));
  return r;
}
// swaps a's upper-half lanes with b's lower-half lanes (gfx950).
static __device__ __forceinline__ void permswap(u32& a, u32& b) {
  asm volatile("v_permlane32_swap_b32 %0, %1" : "+v"(a), "+v"(b));
}

#define GLB(p) ((const __attribute__((address_space(1))) void*)(p))
#define LDS(p) ((__attribute__((address_space(3))) void*)(p))

// ---------------------------------------------------------------------------
// fp32 -> bf16 convert
// ---------------------------------------------------------------------------
__global__ void cvt_bf16_kernel(const float* __restrict__ in,
                                u16* __restrict__ out, int n) {
  int i = (blockIdx.x * 256 + threadIdx.x) * 8;
  if (i >= n) return;
  float4 a = *reinterpret_cast<const float4*>(in + i);
  float4 b = *reinterpret_cast<const float4*>(in + i + 4);
  short8 r;
  r[0] = (short)f2bf(a.x); r[1] = (short)f2bf(a.y);
  r[2] = (short)f2bf(a.z); r[3] = (short)f2bf(a.w);
  r[4] = (short)f2bf(b.x); r[5] = (short)f2bf(b.y);
  r[6] = (short)f2bf(b.z); r[7] = (short)f2bf(b.w);
  *reinterpret_cast<short8*>(out + i) = r;
}

// ---------------------------------------------------------------------------
// RoPE table
// ---------------------------------------------------------------------------
__global__ void rope_tab_kernel(float* __restrict__ ctab, float* __restrict__ stab) {
  int idx = blockIdx.x * 256 + threadIdx.x;
  if (idx >= L_ * (DH / 2)) return;
  int pos = idx >> 6;
  int f = idx & 63;
  float inv_freq = powf(10000.0f, -(float)f * (1.0f / 64.0f));
  float ang = (float)pos * inv_freq;
  float s, c;
  sincosf(ang, &s, &c);
  ctab[idx] = c;
  stab[idx] = s;
}

// ---------------------------------------------------------------------------
// RoPE apply from bf16 fused-qkv buffer -> bf16 head-major buffer
// ---------------------------------------------------------------------------
__global__ void rope_convert_kernel(const u16* __restrict__ in,
                                    u16* __restrict__ outb,
                                    const float* __restrict__ ctab,
                                    const float* __restrict__ stab,
                                    int H, int rowStride, int colOff,
                                    float scale, int total) {
  int idx = blockIdx.x * 256 + threadIdx.x;
  if (idx >= total) return;
  int f = idx & 63;
  int row = idx >> 6;
  int h = row % H;
  int bl = row / H;
  int l = bl & (L_ - 1);
  size_t sbase = (size_t)bl * rowStride + colOff + (size_t)h * DH;
  size_t dbase = (size_t)bl * ((size_t)H * DH) + (size_t)h * DH;
  float x1 = bf2f(in[sbase + f]);
  float x2 = bf2f(in[sbase + 64 + f]);
  float c = ctab[l * 64 + f];
  float s = stab[l * 64 + f];
  outb[dbase + f]      = f2bf((x1 * c - x2 * s) * scale);
  outb[dbase + 64 + f] = f2bf((x2 * c + x1 * s) * scale);
}

// ---------------------------------------------------------------------------
// V transpose from bf16 qkv buffer: -> Vt[(b*HKV+kvh)*128+d][key]
// ---------------------------------------------------------------------------
__global__ __launch_bounds__(256) void transpose_v_kernel(
    const u16* __restrict__ v, u16* __restrict__ Vt,
    int rowStride, int colOff) {
  __shared__ u16 tile[64][68];
  const int k0 = blockIdx.x * 64;
  const int d0 = blockIdx.y * 64;
  const int bk = blockIdx.z;
  const int b = bk / HKV, kvh = bk % HKV;
#pragma unroll
  for (int i = 0; i < 4; ++i) {
    int key = i * 16 + (threadIdx.x >> 4);
    int d4 = (threadIdx.x & 15) * 4;
    *reinterpret_cast<ushort2*>(&tile[key][d4]) = *reinterpret_cast<const ushort2*>(
        &v[(size_t)(b * L_ + k0 + key) * rowStride + colOff + kvh * DH + d0 + d4]);
    *reinterpret_cast<ushort2*>(&tile[key][d4 + 2]) = *reinterpret_cast<const ushort2*>(
        &v[(size_t)(b * L_ + k0 + key) * rowStride + colOff + kvh * DH + d0 + d4 + 2]);
  }
  __syncthreads();
  const int d = threadIdx.x >> 2;
  const int kq = (threadIdx.x & 3) * 16;
  u16* orow = Vt + ((size_t)(bk * DH + d0 + d)) * L_ + k0 + kq;
#pragma unroll
  for (int j = 0; j < 16; ++j) orow[j] = tile[kq + j][d];
}

// ---------------------------------------------------------------------------
// bf16 MFMA GEMM (m97 structure), templated output dtype
// ---------------------------------------------------------------------------
#define GBM 128
#define GBN 128
#define GBK 32

template <bool BF16OUT>
__global__ __launch_bounds__(256) void gemm_bf16_kernel(
    const u16* __restrict__ A, const u16* __restrict__ W,
    const float* __restrict__ bias, void* __restrict__ Cv,
    int M, int N, int K)
{
  __shared__ u16 As[GBM][GBK];
  __shared__ u16 Bs[GBN][GBK];
  const int tid = threadIdx.x;
  const int wave = tid >> 6;
  const int lane = tid & 63;
  const int lr = lane & 15;
  const int lg = lane >> 4;
  const int bm = blockIdx.y * GBM;
  const int bn = blockIdx.x * GBN;
  const int wm = (wave >> 1) * 64;
  const int wn = (wave & 1) * 64;

  const int srow = wave * 16 + (lane >> 2);
  const int scol = (lane & 3) * 8;
  const u16* ga = A + (size_t)(bm + srow) * K + scol;
  const u16* gb = W + (size_t)(bn + srow) * K + scol;
  u16* lA0 = &As[wave * 16][0];
  u16* lA1 = &As[64 + wave * 16][0];
  u16* lB0 = &Bs[wave * 16][0];
  u16* lB1 = &Bs[64 + wave * 16][0];

  f32x4 acc[4][4];
#pragma unroll
  for (int i = 0; i < 4; ++i)
#pragma unroll
    for (int j = 0; j < 4; ++j) acc[i][j] = (f32x4){0.f, 0.f, 0.f, 0.f};

  for (int k0 = 0; k0 < K; k0 += GBK) {
    __syncthreads();
    __builtin_amdgcn_global_load_lds(GLB(ga + k0), LDS(lA0), 16, 0, 0);
    __builtin_amdgcn_global_load_lds(GLB(ga + k0 + (size_t)64 * K), LDS(lA1), 16, 0, 0);
    __builtin_amdgcn_global_load_lds(GLB(gb + k0), LDS(lB0), 16, 0, 0);
    __builtin_amdgcn_global_load_lds(GLB(gb + k0 + (size_t)64 * K), LDS(lB1), 16, 0, 0);
    __syncthreads();

    short8 af[4], bf[4];
#pragma unroll
    for (int mi = 0; mi < 4; ++mi)
      af[mi] = *reinterpret_cast<const short8*>(&As[wm + mi * 16 + lr][lg * 8]);
#pragma unroll
    for (int ni = 0; ni < 4; ++ni)
      bf[ni] = *reinterpret_cast<const short8*>(&Bs[wn + ni * 16 + lr][lg * 8]);
#pragma unroll
    for (int mi = 0; mi < 4; ++mi)
#pragma unroll
      for (int ni = 0; ni < 4; ++ni)
        acc[mi][ni] = __builtin_amdgcn_mfma_f32_16x16x32_bf16(af[mi], bf[ni], acc[mi][ni], 0, 0, 0);
  }

#pragma unroll
  for (int ni = 0; ni < 4; ++ni) {
    int col = bn + wn + ni * 16 + lr;
    float bv = (bias != nullptr) ? bias[col] : 0.f;
#pragma unroll
    for (int mi = 0; mi < 4; ++mi) {
#pragma unroll
      for (int r = 0; r < 4; ++r) {
        int row = bm + wm + mi * 16 + lg * 4 + r;
        float val = acc[mi][ni][r] + bv;
        if constexpr (BF16OUT)
          ((u16*)Cv)[(size_t)row * N + col] = f2bf(val);
        else
          ((float*)Cv)[(size_t)row * N + col] = val;
      }
    }
  }
}

// ---------------------------------------------------------------------------
// Flash attention, LDS K/V shared by 4 heads, counted-vmcnt pipeline (T3/T4).
// Block = 4 waves (256 thr) = 4 heads x one 32-row q-tile; block processes
// tile pair (63-p, p) sequentially -> all 256 blocks do exactly 65 steps.
// Per step: {vmcnt(4); s_barrier; ds_read frags; lgkmcnt(0); s_barrier;
// stage(s+2); MFMA+softmax}. Loads never drain to 0 in the loop.
// ---------------------------------------------------------------------------
__device__ __forceinline__ void head_step(
    const short8 qB[8], const short8 kc[8], const short8 vv[8],
    int j0, int q0, int l5, int hi, float* cbufw,
    f32x16 O[4], float& mrun, float& lrun)
{
  f32x16 accl, acch;
#pragma unroll
  for (int r = 0; r < 16; ++r) { accl[r] = 0.f; acch[r] = 0.f; }
#pragma unroll
  for (int s = 0; s < 4; ++s)
    accl = __builtin_amdgcn_mfma_f32_32x32x16_bf16(kc[s], qB[s], accl, 0, 0, 0);
#pragma unroll
  for (int s = 4; s < 8; ++s)
    acch = __builtin_amdgcn_mfma_f32_32x32x16_bf16(kc[s], qB[s], acch, 0, 0, 0);

  float S[16];
#pragma unroll
  for (int r = 0; r < 16; ++r) S[r] = accl[r] + acch[r];

  if (j0 == q0) {
#pragma unroll
    for (int r = 0; r < 16; ++r) {
      int crow = (r & 3) + 8 * (r >> 2) + 4 * hi;
      if (crow > l5) S[r] = -INFINITY;
    }
  }

  float t8[8], t4[4], t2[2];
#pragma unroll
  for (int r = 0; r < 8; ++r) t8[r] = fmaxf(S[2 * r], S[2 * r + 1]);
#pragma unroll
  for (int r = 0; r < 4; ++r) t4[r] = fmaxf(t8[2 * r], t8[2 * r + 1]);
  t2[0] = fmaxf(t4[0], t4[1]); t2[1] = fmaxf(t4[2], t4[3]);
  float pmax = fmaxf(t2[0], t2[1]);
  pmax = fmaxf(pmax, __shfl_xor(pmax, 32));

  if (__any(pmax > mrun + 8.0f)) {
    float mnew = fmaxf(mrun, pmax);
    float corr = __expf(mrun - mnew);
    mrun = mnew;
    lrun *= corr;
    if (hi == 0) cbufw[l5] = corr;
    float4 cr[4];
#pragma unroll
    for (int g = 0; g < 4; ++g)
      cr[g] = *reinterpret_cast<const float4*>(&cbufw[8 * g + 4 * hi]);
#pragma unroll
    for (int n = 0; n < 4; ++n)
#pragma unroll
      for (int r = 0; r < 16; ++r)
        O[n][r] *= (&cr[r >> 2].x)[r & 3];
  }

  float p[16];
#pragma unroll
  for (int r = 0; r < 16; ++r) p[r] = __expf(S[r] - mrun);
#pragma unroll
  for (int r = 0; r < 8; ++r) t8[r] = p[2 * r] + p[2 * r + 1];
#pragma unroll
  for (int r = 0; r < 4; ++r) t4[r] = t8[2 * r] + t8[2 * r + 1];
  t2[0] = t4[0] + t4[1]; t2[1] = t4[2] + t4[3];
  lrun += t2[0] + t2[1];

  u32 w[8];
#pragma unroll
  for (int t = 0; t < 8; ++t) w[t] = cvt_pk_bf16(p[2 * t], p[2 * t + 1]);
  permswap(w[0], w[2]); permswap(w[1], w[3]);
  permswap(w[4], w[6]); permswap(w[5], w[7]);
  short8 pa0 = __builtin_bit_cast(short8, (u32x4){w[0], w[1], w[2], w[3]});
  short8 pa1 = __builtin_bit_cast(short8, (u32x4){w[4], w[5], w[6], w[7]});

#pragma unroll
  for (int n = 0; n < 4; ++n) {
    O[n] = __builtin_amdgcn_mfma_f32_32x32x16_bf16(pa0, vv[n * 2 + 0], O[n], 0, 0, 0);
    O[n] = __builtin_amdgcn_mfma_f32_32x32x16_bf16(pa1, vv[n * 2 + 1], O[n], 0, 0, 0);
  }
}

__device__ __forceinline__ void head_epilogue(
    const f32x16 O[4], float lrun, int l5, int hi, float* cbufw,
    u16* __restrict__ obase)
{
  float ltot = lrun + __shfl_xor(lrun, 32);
  if (hi == 0) cbufw[l5] = ltot;
  float4 lv[4];
#pragma unroll
  for (int gg = 0; gg < 4; ++gg)
    lv[gg] = *reinterpret_cast<const float4*>(&cbufw[8 * gg + 4 * hi]);
#pragma unroll
  for (int r = 0; r < 16; ++r) {
    int crow = (r & 3) + 8 * (r >> 2) + 4 * hi;
    float inv = __builtin_amdgcn_rcpf((&lv[r >> 2].x)[r & 3]);
    u16* orow = obase + (size_t)crow * (HQ * DH) + l5;
#pragma unroll
    for (int n = 0; n < 4; ++n)
      orow[n * 32] = f2bf(O[n][r] * inv);
  }
}

__global__ __launch_bounds__(256, 1) void flash_attn_pipe_kernel(
    const u16* __restrict__ Qb, const u16* __restrict__ Kb,
    const u16* __restrict__ Vt, u16* __restrict__ ab)
{
  const int tid = threadIdx.x;
  const int wave = tid >> 6;
  const int lane = tid & 63;
  const int l5 = lane & 31;
  const int hi = lane >> 5;

  // 256 blocks: p = pair (0..31), c = combo (b,kvh), hh = head-half
  const int bid = blockIdx.x;
  const int p = bid >> 3;
  const int c = (bid >> 1) & 3;
  const int hh = bid & 1;
  const int b = c >> 1, kvh = c & 1;
  const int h = kvh * 8 + hh * 4 + wave;    // this wave's head
  const int tA = 63 - p, tB = p;            // heavy tile first
  const int bk = b * HKV + kvh;

  __shared__ u16 Ks[2][32 * 128];   // 8 KB each; swizzled slot ^= key&7
  __shared__ u16 Vs[2][128 * 32];   // 8 KB each; swizzled slot ^= (d>>1)&3
  __shared__ __align__(16) float cbuf[4][32];
  float* cbufw = cbuf[wave];

  const u16* Kg = Kb + (size_t)(b * L_) * (HKV * DH) + kvh * DH;
  const u16* Vg = Vt + (size_t)(bk * DH) * L_;

  // staging: global step s -> source j0 (tile A steps 0..tA, then tile B)
  auto jof = [&](int s) { return (s <= tA) ? s * 32 : (s - tA - 1) * 32; };
  auto stage = [&](int s) {
    const int buf = s & 1;
    const int j0 = jof(s);
#pragma unroll
    for (int q = 0; q < 2; ++q) {
      int cnk = (q * 4 + wave) * 64 + lane;   // K chunk 0..511
      int key = cnk >> 4, slot = cnk & 15;
      const u16* src = Kg + (size_t)(j0 + key) * (HKV * DH) + (slot ^ (key & 7)) * 8;
      __builtin_amdgcn_global_load_lds(GLB(src), LDS(&Ks[buf][(q * 4 + wave) * 64 * 8]), 16, 0, 0);
    }
#pragma unroll
    for (int q = 0; q < 2; ++q) {
      int cnk = (q * 4 + wave) * 64 + lane;   // V chunk 0..511
      int d = cnk >> 2, slot = cnk & 3;
      const u16* src = Vg + (size_t)d * L_ + j0 + (slot ^ ((d >> 1) & 3)) * 8;
      __builtin_amdgcn_global_load_lds(GLB(src), LDS(&Vs[buf][(q * 4 + wave) * 64 * 8]), 16, 0, 0);
    }
  };

  stage(0);
  stage(1);

  int s = 0;
#pragma unroll 1
  for (int half = 0; half < 2; ++half) {
    const int t = half ? tB : tA;
    const int q0 = 32 * t;

    // Q fragments for this tile (B-operand of swapped QK^T)
    const u16* qrow = Qb + ((size_t)(b * L_ + q0 + l5)) * (HQ * DH) + h * DH + hi * 8;
    short8 qB[8];
#pragma unroll
    for (int ss = 0; ss < 8; ++ss)
      qB[ss] = *reinterpret_cast<const short8*>(qrow + ss * 16);

    f32x16 O[4];
#pragma unroll
    for (int n = 0; n < 4; ++n)
#pragma unroll
      for (int r = 0; r < 16; ++r) O[n][r] = 0.f;
    float mrun = -INFINITY, lrun = 0.f;

    const int nst = t + 1;
#pragma unroll 1
    for (int k = 0; k < nst; ++k, ++s) {
      // wait for tile s's 4 loads (tile s+1's stay in flight)
      if (s < 64) { asm volatile("s_waitcnt vmcnt(4)" ::: "memory"); }
      else        { asm volatile("s_waitcnt vmcnt(0)" ::: "memory"); }
      __builtin_amdgcn_s_barrier();            // (A) buf[s&1] ready for all
      __builtin_amdgcn_sched_barrier(0);

      const int cur = s & 1;
      short8 kc[8], vv[8];
#pragma unroll
      for (int ss = 0; ss < 8; ++ss) {
        int slot = (2 * ss + hi) ^ (l5 & 7);
        kc[ss] = *reinterpret_cast<const short8*>(&Ks[cur][l5 * 128 + slot * 8]);
      }
#pragma unroll
      for (int n = 0; n < 4; ++n) {
#pragma unroll
        for (int cc = 0; cc < 2; ++cc) {
          int d = n * 32 + l5;
          int slot = (cc * 2 + hi) ^ ((d >> 1) & 3);
          vv[n * 2 + cc] = *reinterpret_cast<const short8*>(&Vs[cur][d * 32 + slot * 8]);
        }
      }
      asm volatile("s_waitcnt lgkmcnt(0)" ::: "memory");
      __builtin_amdgcn_sched_barrier(0);
      __builtin_amdgcn_s_barrier();            // (B) all waves done reading buf[cur]
      if (s + 2 <= 64) stage(s + 2);           // overwrite buf[cur] for tile s+2

      head_step(qB, kc, vv, jof(s), q0, l5, hi, cbufw, O, mrun, lrun);
    }

    u16* obase = ab + (size_t)(b * L_ + q0) * (HQ * DH) + h * DH;
    head_epilogue(O, lrun, l5, hi, cbufw, obase);
  }
}

// ---------------------------------------------------------------------------
// launch
// ---------------------------------------------------------------------------
extern "C" void kernel_launch(void* const* d_in, const int* in_sizes, int n_in,
                              void* d_out, int out_size, void* d_ws, size_t ws_size,
                              hipStream_t stream) {
  const float* x  = (const float*)d_in[0];
  const float* wq = (const float*)d_in[1];
  const float* wk = (const float*)d_in[2];
  const float* wv = (const float*)d_in[3];
  const float* wo = (const float*)d_in[4];
  const float* bq = (const float*)d_in[5];
  const float* bk = (const float*)d_in[6];
  const float* bv = (const float*)d_in[7];
  float* out = (float*)d_out;

  const int M = B_ * L_;
  const int NQKV = HQ * DH + 2 * HKV * DH;  // 2560
  const size_t QN = (size_t)B_ * L_ * HQ * DH;
  const size_t KN = (size_t)B_ * L_ * HKV * DH;
  const size_t TN = (size_t)L_ * (DH / 2);

  float* ws = (float*)d_ws;
  float* ct   = ws;
  float* st   = ct + TN;
  float* bqkv = st + TN;
  u16* qkvb   = (u16*)(bqkv + 2560);        // bf16 QKV projection output
  u16* xb     = qkvb + (size_t)M * NQKV;
  u16* wqkvb  = xb + (size_t)M * E_;
  u16* Qbf    = wqkvb + (size_t)NQKV * E_;
  u16* Kbf    = Qbf + QN;
  u16* Vt     = Kbf + KN;
  u16* ab     = qkvb;   // alias: qkvb dead after rope/transpose
  u16* wob    = Qbf;    // alias: Qbf dead after attention

  const float scale = 0.08838834764831845f;

  rope_tab_kernel<<<(L_ * (DH / 2) + 255) / 256, 256, 0, stream>>>(ct, st);

  cvt_bf16_kernel<<<(int)(QN / 8 / 256), 256, 0, stream>>>(x, xb, (int)QN);
  cvt_bf16_kernel<<<(HQ * DH * E_) / 8 / 256, 256, 0, stream>>>(wq, wqkvb, HQ * DH * E_);
  cvt_bf16_kernel<<<(HKV * DH * E_) / 8 / 256, 256, 0, stream>>>(
      wk, wqkvb + (size_t)(HQ * DH) * E_, HKV * DH * E_);
  cvt_bf16_kernel<<<(HKV * DH * E_) / 8 / 256, 256, 0, stream>>>(
      wv, wqkvb + (size_t)(HQ * DH + HKV * DH) * E_, HKV * DH * E_);

  hipMemcpyAsync(bqkv, bq, (size_t)HQ * DH * 4, hipMemcpyDeviceToDevice, stream);
  hipMemcpyAsync(bqkv + HQ * DH, bk, (size_t)HKV * DH * 4, hipMemcpyDeviceToDevice, stream);
  hipMemcpyAsync(bqkv + HQ * DH + HKV * DH, bv, (size_t)HKV * DH * 4, hipMemcpyDeviceToDevice, stream);

  gemm_bf16_kernel<true><<<dim3(NQKV / GBN, M / GBM), 256, 0, stream>>>(
      xb, wqkvb, bqkv, qkvb, M, NQKV, E_);

  {
    int totq = B_ * L_ * HQ * 64;
    rope_convert_kernel<<<(totq + 255) / 256, 256, 0, stream>>>(
        qkvb, Qbf, ct, st, HQ, NQKV, 0, scale, totq);
    int totk = B_ * L_ * HKV * 64;
    rope_convert_kernel<<<(totk + 255) / 256, 256, 0, stream>>>(
        qkvb, Kbf, ct, st, HKV, NQKV, HQ * DH, 1.0f, totk);
  }
  transpose_v_kernel<<<dim3(L_ / 64, DH / 64, B_ * HKV), 256, 0, stream>>>(
      qkvb, Vt, NQKV, HQ * DH + HKV * DH);

  flash_attn_pipe_kernel<<<dim3(256), 256, 0, stream>>>(Qbf, Kbf, Vt, ab);

  cvt_bf16_kernel<<<(E_ * E_) / 8 / 256, 256, 0, stream>>>(wo, wob, E_ * E_);
  gemm_bf16_kernel<false><<<dim3(E_ / GBN, M / GBM), 256, 0, stream>>>(
      ab, wob, nullptr, out, M, E_, E_);
}

// Round 10
// 234.257 us; speedup vs baseline: 1.4115x; 1.0828x over previous
//
#include <hip/hip_runtime.h>
#include <math.h>

#define B_ 2
#define L_ 2048
#define E_ 2048
#define HQ 16
#define HKV 2
#define DH 128

typedef unsigned short u16;
typedef unsigned int u32;
typedef __attribute__((ext_vector_type(8))) short short8;
typedef __attribute__((ext_vector_type(4))) float f32x4;
typedef __attribute__((ext_vector_type(16))) float f32x16;
typedef __attribute__((ext_vector_type(4))) u32 u32x4;

static __device__ __forceinline__ u16 f2bf(float f) {
  unsigned int u = __float_as_uint(f);
  unsigned int r = (u + 0x7fffu + ((u >> 16) & 1u)) >> 16;
  return (u16)r;
}
static __device__ __forceinline__ float bf2f(u16 v) {
  return __uint_as_float(((u32)v) << 16);
}

static __device__ __forceinline__ u32 cvt_pk_bf16(float lo, float hi) {
  u32 r;
  asm volatile("v_cvt_pk_bf16_f32 %0, %1, %2" : "=v"(r) : "v"(lo), "v"(hi));
  return r;
}
// swaps a's upper-half lanes with b's lower-half lanes (gfx950).
static __device__ __forceinline__ void permswap(u32& a, u32& b) {
  asm volatile("v_permlane32_swap_b32 %0, %1" : "+v"(a), "+v"(b));
}

#define GLB(p) ((const __attribute__((address_space(1))) void*)(p))
#define LDS(p) ((__attribute__((address_space(3))) void*)(p))

// ---------------------------------------------------------------------------
// fp32 -> bf16 convert
// ---------------------------------------------------------------------------
__global__ void cvt_bf16_kernel(const float* __restrict__ in,
                                u16* __restrict__ out, int n) {
  int i = (blockIdx.x * 256 + threadIdx.x) * 8;
  if (i >= n) return;
  float4 a = *reinterpret_cast<const float4*>(in + i);
  float4 b = *reinterpret_cast<const float4*>(in + i + 4);
  short8 r;
  r[0] = (short)f2bf(a.x); r[1] = (short)f2bf(a.y);
  r[2] = (short)f2bf(a.z); r[3] = (short)f2bf(a.w);
  r[4] = (short)f2bf(b.x); r[5] = (short)f2bf(b.y);
  r[6] = (short)f2bf(b.z); r[7] = (short)f2bf(b.w);
  *reinterpret_cast<short8*>(out + i) = r;
}

// ---------------------------------------------------------------------------
// RoPE table
// ---------------------------------------------------------------------------
__global__ void rope_tab_kernel(float* __restrict__ ctab, float* __restrict__ stab) {
  int idx = blockIdx.x * 256 + threadIdx.x;
  if (idx >= L_ * (DH / 2)) return;
  int pos = idx >> 6;
  int f = idx & 63;
  float inv_freq = powf(10000.0f, -(float)f * (1.0f / 64.0f));
  float ang = (float)pos * inv_freq;
  float s, c;
  sincosf(ang, &s, &c);
  ctab[idx] = c;
  stab[idx] = s;
}

// ---------------------------------------------------------------------------
// RoPE apply from bf16 fused-qkv buffer -> bf16 head-major buffer
// ---------------------------------------------------------------------------
__global__ void rope_convert_kernel(const u16* __restrict__ in,
                                    u16* __restrict__ outb,
                                    const float* __restrict__ ctab,
                                    const float* __restrict__ stab,
                                    int H, int rowStride, int colOff,
                                    float scale, int total) {
  int idx = blockIdx.x * 256 + threadIdx.x;
  if (idx >= total) return;
  int f = idx & 63;
  int row = idx >> 6;
  int h = row % H;
  int bl = row / H;
  int l = bl & (L_ - 1);
  size_t sbase = (size_t)bl * rowStride + colOff + (size_t)h * DH;
  size_t dbase = (size_t)bl * ((size_t)H * DH) + (size_t)h * DH;
  float x1 = bf2f(in[sbase + f]);
  float x2 = bf2f(in[sbase + 64 + f]);
  float c = ctab[l * 64 + f];
  float s = stab[l * 64 + f];
  outb[dbase + f]      = f2bf((x1 * c - x2 * s) * scale);
  outb[dbase + 64 + f] = f2bf((x2 * c + x1 * s) * scale);
}

// ---------------------------------------------------------------------------
// V transpose from bf16 qkv buffer: -> Vt[(b*HKV+kvh)*128+d][key]
// ---------------------------------------------------------------------------
__global__ __launch_bounds__(256) void transpose_v_kernel(
    const u16* __restrict__ v, u16* __restrict__ Vt,
    int rowStride, int colOff) {
  __shared__ u16 tile[64][68];
  const int k0 = blockIdx.x * 64;
  const int d0 = blockIdx.y * 64;
  const int bk = blockIdx.z;
  const int b = bk / HKV, kvh = bk % HKV;
#pragma unroll
  for (int i = 0; i < 4; ++i) {
    int key = i * 16 + (threadIdx.x >> 4);
    int d4 = (threadIdx.x & 15) * 4;
    *reinterpret_cast<ushort2*>(&tile[key][d4]) = *reinterpret_cast<const ushort2*>(
        &v[(size_t)(b * L_ + k0 + key) * rowStride + colOff + kvh * DH + d0 + d4]);
    *reinterpret_cast<ushort2*>(&tile[key][d4 + 2]) = *reinterpret_cast<const ushort2*>(
        &v[(size_t)(b * L_ + k0 + key) * rowStride + colOff + kvh * DH + d0 + d4 + 2]);
  }
  __syncthreads();
  const int d = threadIdx.x >> 2;
  const int kq = (threadIdx.x & 3) * 16;
  u16* orow = Vt + ((size_t)(bk * DH + d0 + d)) * L_ + k0 + kq;
#pragma unroll
  for (int j = 0; j < 16; ++j) orow[j] = tile[kq + j][d];
}

// ---------------------------------------------------------------------------
// bf16 MFMA GEMM (m97 structure), templated output dtype
// ---------------------------------------------------------------------------
#define GBM 128
#define GBN 128
#define GBK 32

template <bool BF16OUT>
__global__ __launch_bounds__(256) void gemm_bf16_kernel(
    const u16* __restrict__ A, const u16* __restrict__ W,
    const float* __restrict__ bias, void* __restrict__ Cv,
    int M, int N, int K)
{
  __shared__ u16 As[GBM][GBK];
  __shared__ u16 Bs[GBN][GBK];
  const int tid = threadIdx.x;
  const int wave = tid >> 6;
  const int lane = tid & 63;
  const int lr = lane & 15;
  const int lg = lane >> 4;
  const int bm = blockIdx.y * GBM;
  const int bn = blockIdx.x * GBN;
  const int wm = (wave >> 1) * 64;
  const int wn = (wave & 1) * 64;

  const int srow = wave * 16 + (lane >> 2);
  const int scol = (lane & 3) * 8;
  const u16* ga = A + (size_t)(bm + srow) * K + scol;
  const u16* gb = W + (size_t)(bn + srow) * K + scol;
  u16* lA0 = &As[wave * 16][0];
  u16* lA1 = &As[64 + wave * 16][0];
  u16* lB0 = &Bs[wave * 16][0];
  u16* lB1 = &Bs[64 + wave * 16][0];

  f32x4 acc[4][4];
#pragma unroll
  for (int i = 0; i < 4; ++i)
#pragma unroll
    for (int j = 0; j < 4; ++j) acc[i][j] = (f32x4){0.f, 0.f, 0.f, 0.f};

  for (int k0 = 0; k0 < K; k0 += GBK) {
    __syncthreads();
    __builtin_amdgcn_global_load_lds(GLB(ga + k0), LDS(lA0), 16, 0, 0);
    __builtin_amdgcn_global_load_lds(GLB(ga + k0 + (size_t)64 * K), LDS(lA1), 16, 0, 0);
    __builtin_amdgcn_global_load_lds(GLB(gb + k0), LDS(lB0), 16, 0, 0);
    __builtin_amdgcn_global_load_lds(GLB(gb + k0 + (size_t)64 * K), LDS(lB1), 16, 0, 0);
    __syncthreads();

    short8 af[4], bf[4];
#pragma unroll
    for (int mi = 0; mi < 4; ++mi)
      af[mi] = *reinterpret_cast<const short8*>(&As[wm + mi * 16 + lr][lg * 8]);
#pragma unroll
    for (int ni = 0; ni < 4; ++ni)
      bf[ni] = *reinterpret_cast<const short8*>(&Bs[wn + ni * 16 + lr][lg * 8]);
#pragma unroll
    for (int mi = 0; mi < 4; ++mi)
#pragma unroll
      for (int ni = 0; ni < 4; ++ni)
        acc[mi][ni] = __builtin_amdgcn_mfma_f32_16x16x32_bf16(af[mi], bf[ni], acc[mi][ni], 0, 0, 0);
  }

#pragma unroll
  for (int ni = 0; ni < 4; ++ni) {
    int col = bn + wn + ni * 16 + lr;
    float bv = (bias != nullptr) ? bias[col] : 0.f;
#pragma unroll
    for (int mi = 0; mi < 4; ++mi) {
#pragma unroll
      for (int r = 0; r < 4; ++r) {
        int row = bm + wm + mi * 16 + lg * 4 + r;
        float val = acc[mi][ni][r] + bv;
        if constexpr (BF16OUT)
          ((u16*)Cv)[(size_t)row * N + col] = f2bf(val);
        else
          ((float*)Cv)[(size_t)row * N + col] = val;
      }
    }
  }
}

// ---------------------------------------------------------------------------
// Flash attention, LDS K/V shared by 4 heads, counted-vmcnt pipeline (T3/T4).
// Block = 4 waves (256 thr) = 4 heads x ONE 32-row q-tile. Grid 512 = 2
// blocks/CU: blocks i and i+256 land on the same CU (round-robin dispatch)
// and carry tiles 63-u and u -> 65 steps per CU, latency cross-hidden.
// Per step: {vmcnt(4); s_barrier; ds_read frags; lgkmcnt(0); s_barrier;
// stage(s+2); MFMA+softmax}. Loads never drain to 0 mid-loop.
// ---------------------------------------------------------------------------
__device__ __forceinline__ void head_step(
    const short8 qB[8], const short8 kc[8], const short8 vv[8],
    int j0, int q0, int l5, int hi, float* cbufw,
    f32x16 O[4], float& mrun, float& lrun)
{
  f32x16 accl, acch;
#pragma unroll
  for (int r = 0; r < 16; ++r) { accl[r] = 0.f; acch[r] = 0.f; }
#pragma unroll
  for (int s = 0; s < 4; ++s)
    accl = __builtin_amdgcn_mfma_f32_32x32x16_bf16(kc[s], qB[s], accl, 0, 0, 0);
#pragma unroll
  for (int s = 4; s < 8; ++s)
    acch = __builtin_amdgcn_mfma_f32_32x32x16_bf16(kc[s], qB[s], acch, 0, 0, 0);

  float S[16];
#pragma unroll
  for (int r = 0; r < 16; ++r) S[r] = accl[r] + acch[r];

  if (j0 == q0) {
#pragma unroll
    for (int r = 0; r < 16; ++r) {
      int crow = (r & 3) + 8 * (r >> 2) + 4 * hi;
      if (crow > l5) S[r] = -INFINITY;
    }
  }

  float t8[8], t4[4], t2[2];
#pragma unroll
  for (int r = 0; r < 8; ++r) t8[r] = fmaxf(S[2 * r], S[2 * r + 1]);
#pragma unroll
  for (int r = 0; r < 4; ++r) t4[r] = fmaxf(t8[2 * r], t8[2 * r + 1]);
  t2[0] = fmaxf(t4[0], t4[1]); t2[1] = fmaxf(t4[2], t4[3]);
  float pmax = fmaxf(t2[0], t2[1]);
  pmax = fmaxf(pmax, __shfl_xor(pmax, 32));

  if (__any(pmax > mrun + 8.0f)) {
    float mnew = fmaxf(mrun, pmax);
    float corr = __expf(mrun - mnew);
    mrun = mnew;
    lrun *= corr;
    if (hi == 0) cbufw[l5] = corr;
    float4 cr[4];
#pragma unroll
    for (int g = 0; g < 4; ++g)
      cr[g] = *reinterpret_cast<const float4*>(&cbufw[8 * g + 4 * hi]);
#pragma unroll
    for (int n = 0; n < 4; ++n)
#pragma unroll
      for (int r = 0; r < 16; ++r)
        O[n][r] *= (&cr[r >> 2].x)[r & 3];
  }

  float p[16];
#pragma unroll
  for (int r = 0; r < 16; ++r) p[r] = __expf(S[r] - mrun);
#pragma unroll
  for (int r = 0; r < 8; ++r) t8[r] = p[2 * r] + p[2 * r + 1];
#pragma unroll
  for (int r = 0; r < 4; ++r) t4[r] = t8[2 * r] + t8[2 * r + 1];
  t2[0] = t4[0] + t4[1]; t2[1] = t4[2] + t4[3];
  lrun += t2[0] + t2[1];

  u32 w[8];
#pragma unroll
  for (int t = 0; t < 8; ++t) w[t] = cvt_pk_bf16(p[2 * t], p[2 * t + 1]);
  permswap(w[0], w[2]); permswap(w[1], w[3]);
  permswap(w[4], w[6]); permswap(w[5], w[7]);
  short8 pa0 = __builtin_bit_cast(short8, (u32x4){w[0], w[1], w[2], w[3]});
  short8 pa1 = __builtin_bit_cast(short8, (u32x4){w[4], w[5], w[6], w[7]});

#pragma unroll
  for (int n = 0; n < 4; ++n) {
    O[n] = __builtin_amdgcn_mfma_f32_32x32x16_bf16(pa0, vv[n * 2 + 0], O[n], 0, 0, 0);
    O[n] = __builtin_amdgcn_mfma_f32_32x32x16_bf16(pa1, vv[n * 2 + 1], O[n], 0, 0, 0);
  }
}

__device__ __forceinline__ void head_epilogue(
    const f32x16 O[4], float lrun, int l5, int hi, float* cbufw,
    u16* __restrict__ obase)
{
  float ltot = lrun + __shfl_xor(lrun, 32);
  if (hi == 0) cbufw[l5] = ltot;
  float4 lv[4];
#pragma unroll
  for (int gg = 0; gg < 4; ++gg)
    lv[gg] = *reinterpret_cast<const float4*>(&cbufw[8 * gg + 4 * hi]);
#pragma unroll
  for (int r = 0; r < 16; ++r) {
    int crow = (r & 3) + 8 * (r >> 2) + 4 * hi;
    float inv = __builtin_amdgcn_rcpf((&lv[r >> 2].x)[r & 3]);
    u16* orow = obase + (size_t)crow * (HQ * DH) + l5;
#pragma unroll
    for (int n = 0; n < 4; ++n)
      orow[n * 32] = f2bf(O[n][r] * inv);
  }
}

__global__ __launch_bounds__(256, 2) void flash_attn_pipe_kernel(
    const u16* __restrict__ Qb, const u16* __restrict__ Kb,
    const u16* __restrict__ Vt, u16* __restrict__ ab)
{
  const int tid = threadIdx.x;
  const int wave = tid >> 6;
  const int lane = tid & 63;
  const int l5 = lane & 31;
  const int hi = lane >> 5;

  // 512 blocks: half = heavy/light, u = pair 0..31, x = (combo<<1)|head-half
  const int bid = blockIdx.x;
  const int half = bid >> 8;
  const int u = (bid >> 3) & 31;
  const int x = bid & 7;
  const int c = x >> 1;
  const int hh = x & 1;
  const int b = c >> 1, kvh = c & 1;
  const int h = kvh * 8 + hh * 4 + wave;    // this wave's head
  const int t = half ? u : (63 - u);        // heavy tiles in first 256 blocks
  const int q0 = 32 * t;
  const int nst = t + 1;
  const int bk = b * HKV + kvh;

  __shared__ u16 Ks[2][32 * 128];   // 8 KB each; swizzled slot ^= key&7
  __shared__ u16 Vs[2][128 * 32];   // 8 KB each; swizzled slot ^= (d>>1)&3
  __shared__ __align__(16) float cbuf[4][32];
  float* cbufw = cbuf[wave];

  const u16* Kg = Kb + (size_t)(b * L_) * (HKV * DH) + kvh * DH;
  const u16* Vg = Vt + (size_t)(bk * DH) * L_;

  auto stage = [&](int s) {
    const int buf = s & 1;
    const int j0 = s * 32;
#pragma unroll
    for (int q = 0; q < 2; ++q) {
      int cnk = (q * 4 + wave) * 64 + lane;   // K chunk 0..511
      int key = cnk >> 4, slot = cnk & 15;
      const u16* src = Kg + (size_t)(j0 + key) * (HKV * DH) + (slot ^ (key & 7)) * 8;
      __builtin_amdgcn_global_load_lds(GLB(src), LDS(&Ks[buf][(q * 4 + wave) * 64 * 8]), 16, 0, 0);
    }
#pragma unroll
    for (int q = 0; q < 2; ++q) {
      int cnk = (q * 4 + wave) * 64 + lane;   // V chunk 0..511
      int d = cnk >> 2, slot = cnk & 3;
      const u16* src = Vg + (size_t)d * L_ + j0 + (slot ^ ((d >> 1) & 3)) * 8;
      __builtin_amdgcn_global_load_lds(GLB(src), LDS(&Vs[buf][(q * 4 + wave) * 64 * 8]), 16, 0, 0);
    }
  };

  // Q fragments (B-operand of swapped QK^T)
  const u16* qrow = Qb + ((size_t)(b * L_ + q0 + l5)) * (HQ * DH) + h * DH + hi * 8;
  short8 qB[8];
#pragma unroll
  for (int ss = 0; ss < 8; ++ss)
    qB[ss] = *reinterpret_cast<const short8*>(qrow + ss * 16);

  f32x16 O[4];
#pragma unroll
  for (int n = 0; n < 4; ++n)
#pragma unroll
    for (int r = 0; r < 16; ++r) O[n][r] = 0.f;
  float mrun = -INFINITY, lrun = 0.f;

  stage(0);
  if (nst > 1) stage(1);

#pragma unroll 1
  for (int s = 0; s < nst; ++s) {
    if (s + 1 < nst) { asm volatile("s_waitcnt vmcnt(4)" ::: "memory"); }
    else             { asm volatile("s_waitcnt vmcnt(0)" ::: "memory"); }
    __builtin_amdgcn_s_barrier();            // (A) buf[s&1] ready for all
    __builtin_amdgcn_sched_barrier(0);

    const int cur = s & 1;
    short8 kc[8], vv[8];
#pragma unroll
    for (int ss = 0; ss < 8; ++ss) {
      int slot = (2 * ss + hi) ^ (l5 & 7);
      kc[ss] = *reinterpret_cast<const short8*>(&Ks[cur][l5 * 128 + slot * 8]);
    }
#pragma unroll
    for (int n = 0; n < 4; ++n) {
#pragma unroll
      for (int cc = 0; cc < 2; ++cc) {
        int d = n * 32 + l5;
        int slot = (cc * 2 + hi) ^ ((d >> 1) & 3);
        vv[n * 2 + cc] = *reinterpret_cast<const short8*>(&Vs[cur][d * 32 + slot * 8]);
      }
    }
    asm volatile("s_waitcnt lgkmcnt(0)" ::: "memory");
    __builtin_amdgcn_sched_barrier(0);
    __builtin_amdgcn_s_barrier();            // (B) all waves done reading buf[cur]
    if (s + 2 < nst) stage(s + 2);           // overwrite buf[cur] for step s+2

    head_step(qB, kc, vv, s * 32, q0, l5, hi, cbufw, O, mrun, lrun);
  }

  u16* obase = ab + (size_t)(b * L_ + q0) * (HQ * DH) + h * DH;
  head_epilogue(O, lrun, l5, hi, cbufw, obase);
}

// ---------------------------------------------------------------------------
// launch
// ---------------------------------------------------------------------------
extern "C" void kernel_launch(void* const* d_in, const int* in_sizes, int n_in,
                              void* d_out, int out_size, void* d_ws, size_t ws_size,
                              hipStream_t stream) {
  const float* x  = (const float*)d_in[0];
  const float* wq = (const float*)d_in[1];
  const float* wk = (const float*)d_in[2];
  const float* wv = (const float*)d_in[3];
  const float* wo = (const float*)d_in[4];
  const float* bq = (const float*)d_in[5];
  const float* bk = (const float*)d_in[6];
  const float* bv = (const float*)d_in[7];
  float* out = (float*)d_out;

  const int M = B_ * L_;
  const int NQKV = HQ * DH + 2 * HKV * DH;  // 2560
  const size_t QN = (size_t)B_ * L_ * HQ * DH;
  const size_t KN = (size_t)B_ * L_ * HKV * DH;
  const size_t TN = (size_t)L_ * (DH / 2);

  float* ws = (float*)d_ws;
  float* ct   = ws;
  float* st   = ct + TN;
  float* bqkv = st + TN;
  u16* qkvb   = (u16*)(bqkv + 2560);        // bf16 QKV projection output
  u16* xb     = qkvb + (size_t)M * NQKV;
  u16* wqkvb  = xb + (size_t)M * E_;
  u16* Qbf    = wqkvb + (size_t)NQKV * E_;
  u16* Kbf    = Qbf + QN;
  u16* Vt     = Kbf + KN;
  u16* ab     = qkvb;   // alias: qkvb dead after rope/transpose
  u16* wob    = Qbf;    // alias: Qbf dead after attention

  const float scale = 0.08838834764831845f;

  rope_tab_kernel<<<(L_ * (DH / 2) + 255) / 256, 256, 0, stream>>>(ct, st);

  cvt_bf16_kernel<<<(int)(QN / 8 / 256), 256, 0, stream>>>(x, xb, (int)QN);
  cvt_bf16_kernel<<<(HQ * DH * E_) / 8 / 256, 256, 0, stream>>>(wq, wqkvb, HQ * DH * E_);
  cvt_bf16_kernel<<<(HKV * DH * E_) / 8 / 256, 256, 0, stream>>>(
      wk, wqkvb + (size_t)(HQ * DH) * E_, HKV * DH * E_);
  cvt_bf16_kernel<<<(HKV * DH * E_) / 8 / 256, 256, 0, stream>>>(
      wv, wqkvb + (size_t)(HQ * DH + HKV * DH) * E_, HKV * DH * E_);

  hipMemcpyAsync(bqkv, bq, (size_t)HQ * DH * 4, hipMemcpyDeviceToDevice, stream);
  hipMemcpyAsync(bqkv + HQ * DH, bk, (size_t)HKV * DH * 4, hipMemcpyDeviceToDevice, stream);
  hipMemcpyAsync(bqkv + HQ * DH + HKV * DH, bv, (size_t)HKV * DH * 4, hipMemcpyDeviceToDevice, stream);

  gemm_bf16_kernel<true><<<dim3(NQKV / GBN, M / GBM), 256, 0, stream>>>(
      xb, wqkvb, bqkv, qkvb, M, NQKV, E_);

  {
    int totq = B_ * L_ * HQ * 64;
    rope_convert_kernel<<<(totq + 255) / 256, 256, 0, stream>>>(
        qkvb, Qbf, ct, st, HQ, NQKV, 0, scale, totq);
    int totk = B_ * L_ * HKV * 64;
    rope_convert_kernel<<<(totk + 255) / 256, 256, 0, stream>>>(
        qkvb, Kbf, ct, st, HKV, NQKV, HQ * DH, 1.0f, totk);
  }
  transpose_v_kernel<<<dim3(L_ / 64, DH / 64, B_ * HKV), 256, 0, stream>>>(
      qkvb, Vt, NQKV, HQ * DH + HKV * DH);

  flash_attn_pipe_kernel<<<dim3(512), 256, 0, stream>>>(Qbf, Kbf, Vt, ab);

  cvt_bf16_kernel<<<(E_ * E_) / 8 / 256, 256, 0, stream>>>(wo, wob, E_ * E_);
  gemm_bf16_kernel<false><<<dim3(E_ / GBN, M / GBM), 256, 0, stream>>>(
      ab, wob, nullptr, out, M, E_, E_);
}